// Round 2
// baseline (119230.737 us; speedup 1.0000x reference)
//
#include <hip/hip_runtime.h>
#include <cstdint>
#include <cstddef>

#define BB 128
#define TT 512
#define VV 512
#define EE 512
#define HH 1024
#define NBLK 256
#define NTHR 512
#define BHS ((size_t)BB * HH)

// ---------- threefry2x32, JAX partitionable scheme. VERIFIED — do not touch. ----------
__device__ __forceinline__ float tf_uniform(unsigned i) {
  unsigned x0 = 0u;
  unsigned x1 = i;
  const unsigned k0 = 0u, k1 = 1u, k2 = 0x1BD11BDBu;
  x0 += k0; x1 += k1;
#define ROTL_(v, r) (((v) << (r)) | ((v) >> (32 - (r))))
#define RND_(r) { x0 += x1; x1 = ROTL_(x1, (r)); x1 ^= x0; }
  RND_(13) RND_(15) RND_(26) RND_(6)   x0 += k1; x1 += k2 + 1u;
  RND_(17) RND_(29) RND_(16) RND_(24)  x0 += k2; x1 += k0 + 2u;
  RND_(13) RND_(15) RND_(26) RND_(6)   x0 += k0; x1 += k1 + 3u;
  RND_(17) RND_(29) RND_(16) RND_(24)  x0 += k1; x1 += k2 + 4u;
  RND_(13) RND_(15) RND_(26) RND_(6)   x0 += k2; x1 += k0 + 5u;
#undef RND_
#undef ROTL_
  unsigned bits = x0 ^ x1;
  unsigned fb = (bits >> 9) | 0x3f800000u;
  return __uint_as_float(fb) - 1.0f;
}

__device__ __forceinline__ float4 ld4(const float* p) { return *(const float4*)(p); }

// ---------- grid barrier: monotonic counter, agent scope (validated round 1) ----------
__device__ __forceinline__ void gridbar(unsigned* bar, unsigned target) {
  __syncthreads();
  if (threadIdx.x == 0) {
    __threadfence();
    __hip_atomic_fetch_add(bar, 1u, __ATOMIC_RELAXED, __HIP_MEMORY_SCOPE_AGENT);
    while (__hip_atomic_fetch_add(bar, 0u, __ATOMIC_RELAXED, __HIP_MEMORY_SCOPE_AGENT) < target) {
      __builtin_amdgcn_s_sleep(1);
    }
    __threadfence();
  }
  __syncthreads();
}

__global__ __launch_bounds__(256) void init_kernel(float* __restrict__ wsf,
                                                   unsigned* __restrict__ bar) {
  size_t tid = (size_t)blockIdx.x * 256 + threadIdx.x;
  if (tid == 0) *bar = 0u;
  if (tid < 6 * BHS) wsf[tid] = 0.f;
}

// ============================================================================
// Persistent kernel: 256 blocks x 512 threads (8 waves -> 2/SIMD), weights in VGPRs.
// h,c stored row-major [B][H]. Block bn owns units bn*4..+3 (16 gate cols).
// Thread: col c16 = lane&15 (gate g=c16>>2, unit j=c16&3), K-slice s32 = wave*4 + lane>>4.
// x rows staged to LDS (padded slice stride -> conflict-free broadcast reads).
// Reduce: 2x shfl_xor in-wave + fixed-order 8-wave LDS tree (deterministic).
// fc: block (rb=bn&3: 32 rows, cb=bn>>2: 8 cols), slice s64 = wave*8 + lane>>3.
// ============================================================================
__global__ __launch_bounds__(NTHR, 2) void lstm_persistent(
    const int* __restrict__ seq,
    const float* __restrict__ teacher_p,
    const float* __restrict__ emb,
    const float* __restrict__ Wih0, const float* __restrict__ Whh0,
    const float* __restrict__ bih0, const float* __restrict__ bhh0,
    const float* __restrict__ Wih1, const float* __restrict__ Whh1,
    const float* __restrict__ bih1, const float* __restrict__ bhh1,
    const float* __restrict__ fcw, const float* __restrict__ fcb,
    float* __restrict__ out,
    float* __restrict__ h0T, float* __restrict__ c0,
    float* __restrict__ h1T, float* __restrict__ c1,
    unsigned long long* __restrict__ fcpart,
    unsigned* __restrict__ bar) {
  __shared__ float xbuf[8704];        // 34816 B: 4 rows x 2176 (P2 layout, max)
  __shared__ float gacc[BB][17];      // 8704 B
  __shared__ float scr[8][4][17];     // 2176 B
  __shared__ int   tok_s[BB];

  const int tid   = threadIdx.x;
  const int bn    = blockIdx.x;
  const int w     = tid >> 6;
  const int lane  = tid & 63;
  const int c16   = lane & 15;
  const int squad = lane >> 4;
  const int s32   = (w << 2) | squad;      // 0..31
  const int c8    = lane & 7;
  const int oct   = lane >> 3;
  const int s64   = (w << 3) | oct;        // 0..63
  const int grow  = (c16 >> 2) * HH + (bn << 2) + (c16 & 3);
  const int rb    = bn & 3, cb = bn >> 2;
  const int ucell = (bn << 2) + (tid & 3);

  // ---- persistent weight registers (loaded once) ----
  float4 w0r[12], w1r[16], wfr[4];
  {
    const int k0 = s32 * 48;
#pragma unroll
    for (int q = 0; q < 12; ++q) {
      int k = k0 + (q << 2);
      w0r[q] = (k < EE) ? ld4(Wih0 + (size_t)grow * EE + k)
                        : ld4(Whh0 + (size_t)grow * HH + (k - EE));
    }
  }
  {
    const int k0 = s32 * 64;
#pragma unroll
    for (int q = 0; q < 16; ++q) {
      int k = k0 + (q << 2);
      w1r[q] = (k < HH) ? ld4(Wih1 + (size_t)grow * HH + k)
                        : ld4(Whh1 + (size_t)grow * HH + (k - HH));
    }
  }
  {
    const float* wrow = fcw + (size_t)((cb << 3) + c8) * HH + s64 * 16;
#pragma unroll
    for (int q = 0; q < 4; ++q) wfr[q] = ld4(wrow + (q << 2));
  }
  float bc0[4], bc1[4];
#pragma unroll
  for (int g = 0; g < 4; ++g) {
    bc0[g] = bih0[g * HH + ucell] + bhh0[g * HH + ucell];
    bc1[g] = bih1[g * HH + ucell] + bhh1[g * HH + ucell];
  }
  const float tp = teacher_p[0];
  unsigned target = 0;

  for (int t = 0; t < TT; ++t) {
    const float* h0r = h0T + (size_t)(t & 1) * BHS;
    float*       h0w = h0T + (size_t)((t + 1) & 1) * BHS;
    const float* h1r = h1T + (size_t)(t & 1) * BHS;
    float*       h1w = h1T + (size_t)((t + 1) & 1) * BHS;

    // ---------------- token select (redundant per block, deterministic) ----------------
    {
      int b = tid >> 2, qd = tid & 3;
      unsigned long long best = 0ull;
      if (t > 0) {
        const unsigned long long* fp = fcpart + ((size_t)b << 6);
#pragma unroll 4
        for (int i = 0; i < 16; ++i) {
          unsigned long long k2 = fp[(i << 2) + qd];
          if (k2 > best) best = k2;
        }
        unsigned long long o1 = __shfl_xor(best, 1);
        if (o1 > best) best = o1;
        unsigned long long o2 = __shfl_xor(best, 2);
        if (o2 > best) best = o2;
      }
      if (qd == 0) {
        int sel;
        if (t == 0) {
          sel = seq[(size_t)b * TT];
        } else {
          float uu = tf_uniform((unsigned)(t * BB + b));
          sel = (uu < tp) ? seq[(size_t)b * TT + t]
                          : (int)(0xFFFFFFFFu - (unsigned)(best & 0xFFFFFFFFull));
        }
        tok_s[b] = sel;
      }
    }
    __syncthreads();

    // ---------------- P1: layer0 gates (K=1536, Kc=48) + cell0 ----------------
    {
      float4 sg[3];
      auto loadP1 = [&](int bt) {
#pragma unroll
        for (int i = 0; i < 3; ++i) {
          int u = tid + (i << 9);          // < 1536
          int row = u / 384;               // 0..3 (384 f4 per row)
          int k = (u - row * 384) << 2;    // 0..1532
          int b = (bt << 2) + row;
          float4 v;
          if (k < EE) {
            int tk = tok_s[b];
            v = tk ? ld4(emb + (size_t)tk * EE + k) : make_float4(0.f, 0.f, 0.f, 0.f);
          } else {
            v = ld4(h0r + (size_t)b * HH + (k - EE));
          }
          sg[i] = v;
        }
      };
      auto writeP1 = [&]() {
#pragma unroll
        for (int i = 0; i < 3; ++i) {
          int u = tid + (i << 9);
          int row = u / 384;
          int k = (u - row * 384) << 2;
          int dst = row * 1664 + (k / 48) * 52 + (k % 48);   // padded slice stride 52
          *(float4*)(xbuf + dst) = sg[i];
        }
      };
      loadP1(0); writeP1(); __syncthreads();
      for (int bt = 0; bt < 32; ++bt) {
        if (bt < 31) loadP1(bt + 1);       // issue early (T14)
        const float* xp0 = xbuf + s32 * 52;
#pragma unroll 2
        for (int r = 0; r < 4; ++r) {
          const float* xp = xp0 + r * 1664;
          float a0 = 0.f, a1 = 0.f, a2 = 0.f, a3 = 0.f;
#pragma unroll
          for (int q = 0; q < 12; ++q) {
            float4 xv = *(const float4*)(xp + (q << 2));
            a0 = fmaf(xv.x, w0r[q].x, a0);
            a1 = fmaf(xv.y, w0r[q].y, a1);
            a2 = fmaf(xv.z, w0r[q].z, a2);
            a3 = fmaf(xv.w, w0r[q].w, a3);
          }
          float acc = (a0 + a1) + (a2 + a3);
          acc += __shfl_xor(acc, 16);
          acc += __shfl_xor(acc, 32);
          if (squad == 0) scr[w][r][c16] = acc;
        }
        __syncthreads();                   // reads of xbuf + scr done
        if (tid < 64) {
          int r = tid >> 4, c = tid & 15;
          float s = 0.f;
#pragma unroll
          for (int ww = 0; ww < 8; ++ww) s += scr[ww][r][c];
          gacc[(bt << 2) + r][c] = s;
        }
        if (bt < 31) writeP1();            // write next batch after reads drained
        __syncthreads();
      }
      // fused cell0
      {
        int b = tid >> 2, j = tid & 3;
        float gi = gacc[b][j]      + bc0[0];
        float gf = gacc[b][4 + j]  + bc0[1];
        float gg = gacc[b][8 + j]  + bc0[2];
        float go = gacc[b][12 + j] + bc0[3];
        float i_ = 1.f / (1.f + expf(-gi));
        float f_ = 1.f / (1.f + expf(-gf));
        float g_ = tanhf(gg);
        float o_ = 1.f / (1.f + expf(-go));
        size_t off = (size_t)b * HH + ucell;
        float cn = f_ * c0[off] + i_ * g_;
        c0[off] = cn;
        h0w[off] = o_ * tanhf(cn);
      }
    }
    target += NBLK; gridbar(bar, target);

    // ---------------- P2: layer1 gates (K=2048, Kc=64) + cell1 ----------------
    {
      float4 sg[4];
      auto loadP2 = [&](int bt) {
#pragma unroll
        for (int i = 0; i < 4; ++i) {
          int u = tid + (i << 9);          // < 2048
          int row = u >> 9;                // 0..3 (512 f4 per row)
          int k = (u & 511) << 2;          // 0..2044
          int b = (bt << 2) + row;
          sg[i] = (k < HH) ? ld4(h0w + (size_t)b * HH + k)
                           : ld4(h1r + (size_t)b * HH + (k - HH));
        }
      };
      auto writeP2 = [&]() {
#pragma unroll
        for (int i = 0; i < 4; ++i) {
          int u = tid + (i << 9);
          int row = u >> 9;
          int k = (u & 511) << 2;
          int dst = row * 2176 + (k >> 6) * 68 + (k & 63);   // padded slice stride 68
          *(float4*)(xbuf + dst) = sg[i];
        }
      };
      loadP2(0); writeP2(); __syncthreads();
      for (int bt = 0; bt < 32; ++bt) {
        if (bt < 31) loadP2(bt + 1);
        const float* xp0 = xbuf + s32 * 68;
#pragma unroll 2
        for (int r = 0; r < 4; ++r) {
          const float* xp = xp0 + r * 2176;
          float a0 = 0.f, a1 = 0.f, a2 = 0.f, a3 = 0.f;
#pragma unroll
          for (int q = 0; q < 16; ++q) {
            float4 xv = *(const float4*)(xp + (q << 2));
            a0 = fmaf(xv.x, w1r[q].x, a0);
            a1 = fmaf(xv.y, w1r[q].y, a1);
            a2 = fmaf(xv.z, w1r[q].z, a2);
            a3 = fmaf(xv.w, w1r[q].w, a3);
          }
          float acc = (a0 + a1) + (a2 + a3);
          acc += __shfl_xor(acc, 16);
          acc += __shfl_xor(acc, 32);
          if (squad == 0) scr[w][r][c16] = acc;
        }
        __syncthreads();
        if (tid < 64) {
          int r = tid >> 4, c = tid & 15;
          float s = 0.f;
#pragma unroll
          for (int ww = 0; ww < 8; ++ww) s += scr[ww][r][c];
          gacc[(bt << 2) + r][c] = s;
        }
        if (bt < 31) writeP2();
        __syncthreads();
      }
      // fused cell1
      {
        int b = tid >> 2, j = tid & 3;
        float gi = gacc[b][j]      + bc1[0];
        float gf = gacc[b][4 + j]  + bc1[1];
        float gg = gacc[b][8 + j]  + bc1[2];
        float go = gacc[b][12 + j] + bc1[3];
        float i_ = 1.f / (1.f + expf(-gi));
        float f_ = 1.f / (1.f + expf(-gf));
        float g_ = tanhf(gg);
        float o_ = 1.f / (1.f + expf(-go));
        size_t off = (size_t)b * HH + ucell;
        float cn = f_ * c1[off] + i_ * g_;
        c1[off] = cn;
        h1w[off] = o_ * tanhf(cn);
      }
    }
    target += NBLK; gridbar(bar, target);

    // ---------------- fc: logits + argmax partial keys (K=1024, Kc=16) ----------------
    {
      float4 sg[2];
      auto loadF = [&](int bt) {
#pragma unroll
        for (int i = 0; i < 2; ++i) {
          int u = tid + (i << 9);          // < 1024
          int row = u >> 8;                // 0..3 (256 f4 per row)
          int k = (u & 255) << 2;
          int b = (rb << 5) + (bt << 2) + row;
          sg[i] = ld4(h1w + (size_t)b * HH + k);
        }
      };
      auto writeF = [&]() {
#pragma unroll
        for (int i = 0; i < 2; ++i) {
          int u = tid + (i << 9);
          int row = u >> 8;
          int k = (u & 255) << 2;
          int dst = row * 1280 + (k >> 4) * 20 + (k & 15);   // padded slice stride 20
          *(float4*)(xbuf + dst) = sg[i];
        }
      };
      loadF(0); writeF(); __syncthreads();
      for (int bt = 0; bt < 8; ++bt) {
        if (bt < 7) loadF(bt + 1);
        const float* xp0 = xbuf + s64 * 20;
#pragma unroll 2
        for (int r = 0; r < 4; ++r) {
          const float* xp = xp0 + r * 1280;
          float a0 = 0.f, a1 = 0.f, a2 = 0.f, a3 = 0.f;
#pragma unroll
          for (int q = 0; q < 4; ++q) {
            float4 xv = *(const float4*)(xp + (q << 2));
            a0 = fmaf(xv.x, wfr[q].x, a0);
            a1 = fmaf(xv.y, wfr[q].y, a1);
            a2 = fmaf(xv.z, wfr[q].z, a2);
            a3 = fmaf(xv.w, wfr[q].w, a3);
          }
          float acc = (a0 + a1) + (a2 + a3);
          acc += __shfl_xor(acc, 8);
          acc += __shfl_xor(acc, 16);
          acc += __shfl_xor(acc, 32);
          if (oct == 0) scr[w][r][c8] = acc;
        }
        __syncthreads();
        if (tid < 32) {
          int r = tid >> 3, c = tid & 7;
          float s = 0.f;
#pragma unroll
          for (int ww = 0; ww < 8; ++ww) s += scr[ww][r][c];
          int n = (cb << 3) + c;
          float lg = s + fcb[n];
          int b = (rb << 5) + (bt << 2) + r;
          out[((size_t)b * TT + t) * VV + n] = lg;
          unsigned sbits = __float_as_uint(lg);
          sbits = (sbits & 0x80000000u) ? ~sbits : (sbits | 0x80000000u);
          unsigned long long key = ((unsigned long long)sbits << 32) |
                                   (unsigned long long)(0xFFFFFFFFu - (unsigned)n);
#pragma unroll
          for (int off = 4; off > 0; off >>= 1) {
            unsigned long long o = __shfl_down(key, off, 8);
            if (o > key) key = o;
          }
          if (c == 0) fcpart[((size_t)b << 6) + cb] = key;
        }
        if (bt < 7) writeF();
        __syncthreads();
      }
    }
    target += NBLK; gridbar(bar, target);
  }
}

extern "C" void kernel_launch(void* const* d_in, const int* in_sizes, int n_in,
                              void* d_out, int out_size, void* d_ws, size_t ws_size,
                              hipStream_t stream) {
  const int*   seq       = (const int*)d_in[0];
  const float* teacher_p = (const float*)d_in[2];
  const float* embeds    = (const float*)d_in[3];
  const float* W_ih0     = (const float*)d_in[4];
  const float* W_hh0     = (const float*)d_in[5];
  const float* b_ih0     = (const float*)d_in[6];
  const float* b_hh0     = (const float*)d_in[7];
  const float* W_ih1     = (const float*)d_in[8];
  const float* W_hh1     = (const float*)d_in[9];
  const float* b_ih1     = (const float*)d_in[10];
  const float* b_hh1     = (const float*)d_in[11];
  const float* fc_w      = (const float*)d_in[12];
  const float* fc_b      = (const float*)d_in[13];
  float* out = (float*)d_out;

  // workspace: h0(2) | c0 | h1(2) | c1  ([B][H] row-major) | fcpart 64KB | bar
  char* ws = (char*)d_ws;
  float* h0 = (float*)(ws);
  float* c0 = (float*)(ws + 2 * BHS * 4);
  float* h1 = (float*)(ws + 3 * BHS * 4);
  float* c1 = (float*)(ws + 5 * BHS * 4);
  unsigned long long* fcpart = (unsigned long long*)(ws + 6 * BHS * 4);
  unsigned* bar = (unsigned*)(ws + 6 * BHS * 4 + 65536);

  init_kernel<<<3072, 256, 0, stream>>>((float*)ws, bar);

  void* args[] = {
    (void*)&seq, (void*)&teacher_p, (void*)&embeds,
    (void*)&W_ih0, (void*)&W_hh0, (void*)&b_ih0, (void*)&b_hh0,
    (void*)&W_ih1, (void*)&W_hh1, (void*)&b_ih1, (void*)&b_hh1,
    (void*)&fc_w, (void*)&fc_b, (void*)&out,
    (void*)&h0, (void*)&c0, (void*)&h1, (void*)&c1,
    (void*)&fcpart, (void*)&bar
  };
  hipError_t err = hipLaunchCooperativeKernel((void*)lstm_persistent,
                                              dim3(NBLK), dim3(NTHR), args, 0, stream);
  if (err != hipSuccess) {
    // fallback: plain launch; 256 blocks x 512 thr (46KB LDS, LB(512,2)) are
    // trivially co-resident on 256 CUs; barrier remains sound.
    lstm_persistent<<<dim3(NBLK), dim3(NTHR), 0, stream>>>(
        seq, teacher_p, embeds, W_ih0, W_hh0, b_ih0, b_hh0,
        W_ih1, W_hh1, b_ih1, b_hh1, fc_w, fc_b, out,
        h0, c0, h1, c1, fcpart, bar);
  }
}